// Round 4
// baseline (248.870 us; speedup 1.0000x reference)
//
#include <hip/hip_runtime.h>
#include <math.h>

#define BN_EPS 1e-5f
#define ROWS 64

typedef __attribute__((ext_vector_type(8))) short short8;
typedef __attribute__((ext_vector_type(4))) float float4v;

__device__ __forceinline__ unsigned short f2bf(float f) {
    union { float f; unsigned int u; } v; v.f = f;
    unsigned int r = v.u + 0x7FFF + ((v.u >> 16) & 1);   // RNE
    return (unsigned short)(r >> 16);
}
__device__ __forceinline__ float softplus_f(float v) {
    float r = log1pf(__expf(-fabsf(v)));
    return v > 0.f ? v + r : r;
}
__device__ __forceinline__ float swish_f(float a) {
    return a / (1.f + __expf(-a));
}

// ---- prep: coalesced LDS-tiled transposes + BN fold into W0/b0 ----
// grid = 28 blocks x 256:
//   0..23  : W2 [128][1504] -> Wt2 [1536][128] bf16 (col remap d*47+j -> d*48+j, j=47 pad)
//   24..25 : W1 [128][128]  -> Wt1 [128][128] bf16
//   26     : W0 fold: Wt0[n][k] = bf16(W0[k][n]*a[k]) (k<48, pad to 64); b0p = b0 + bsh @ W0
//   27     : b2 pad -> b2p [32][48]
__global__ void prep_weights(const float* __restrict__ W0, const float* __restrict__ W1,
                             const float* __restrict__ W2, const float* __restrict__ b0,
                             const float* __restrict__ b2,
                             const float* __restrict__ bn_scale, const float* __restrict__ bn_bias,
                             const float* __restrict__ bn_mean, const float* __restrict__ bn_var,
                             unsigned short* __restrict__ Wt0, unsigned short* __restrict__ Wt1,
                             unsigned short* __restrict__ Wt2, float* __restrict__ b0p,
                             float* __restrict__ b2p) {
    __shared__ float lds[64 * 129 + 128];
    const int bid = blockIdx.x, tid = threadIdx.x;
    if (bid < 26) {
        const float* src;
        int rstride, c0;
        bool remap;
        if (bid < 24) { src = W2; rstride = 1504; c0 = bid * 64; remap = true; }
        else          { src = W1; rstride = 128;  c0 = (bid - 24) * 64; remap = false; }
        const int cl = tid & 63;
        const int cd = c0 + cl;
        int scol = cd;
        bool valid = true;
        if (remap) {
            int dd = cd / 48, j = cd - dd * 48;
            valid = (j < 47);
            scol = dd * 47 + j;
        }
        #pragma unroll 4
        for (int it = 0; it < 32; ++it) {
            int k = (tid >> 6) + it * 4;
            lds[cl * 129 + k] = valid ? src[k * rstride + scol] : 0.f;   // coalesced read
        }
        __syncthreads();
        unsigned short* dst = (bid < 24) ? Wt2 : Wt1;
        #pragma unroll 4
        for (int it = 0; it < 32; ++it) {
            int cl2 = (tid >> 7) + it * 2;
            int k = tid & 127;
            dst[(size_t)(c0 + cl2) * 128 + k] = f2bf(lds[cl2 * 129 + k]);  // coalesced write
        }
        return;
    }
    if (bid == 26) {
        float* a   = lds + 48 * 129;
        float* bsh = a + 48;
        if (tid < 48) {
            float av = bn_scale[tid] * rsqrtf(bn_var[tid] + BN_EPS);
            a[tid] = av;
            bsh[tid] = bn_bias[tid] - bn_mean[tid] * av;
        }
        for (int idx = tid; idx < 48 * 128; idx += 256) {
            int k = idx >> 7, n = idx & 127;
            lds[k * 129 + n] = W0[k * 128 + n];
        }
        __syncthreads();
        #pragma unroll 4
        for (int it = 0; it < 32; ++it) {
            int n = (tid >> 6) + it * 4;
            int k = tid & 63;
            float v = (k < 48) ? lds[k * 129 + n] * a[k] : 0.f;
            Wt0[n * 64 + k] = f2bf(v);
        }
        if (tid < 128) {
            float s = b0[tid];
            #pragma unroll
            for (int k = 0; k < 48; ++k) s += bsh[k] * lds[k * 129 + tid];
            b0p[tid] = s;
        }
        return;
    }
    for (int e = tid; e < 32 * 48; e += 256) {
        int dd = e / 48, j = e - dd * 48;
        b2p[e] = (j < 47) ? b2[dd * 47 + j] : 0.f;
    }
}

__launch_bounds__(256, 4)
__global__ void nsc_mfma(const float* __restrict__ x, const float* __restrict__ c,
                         const unsigned short* __restrict__ Wt0, const float* __restrict__ b0p,
                         const unsigned short* __restrict__ Wt1, const float* __restrict__ b1,
                         const unsigned short* __restrict__ Wt2, const float* __restrict__ b2p,
                         float* __restrict__ out, int N) {
    // region A [0,17408):       h0 [64][72] bf16  ->  h2 [64][136] bf16
    // region B [17408,38912):   h1 [64][136] bf16 ->  pw 4x[64][20] f32 (20480) + ldp [4][64] f32
    __shared__ __align__(16) char smem[38912];
    unsigned short* h0 = (unsigned short*)smem;            // stride 72
    unsigned short* h2 = (unsigned short*)smem;            // stride 136
    unsigned short* h1 = (unsigned short*)(smem + 17408);  // stride 136
    float*          ldp = (float*)(smem + 17408 + 20480);  // [4][64]

    const int tid  = threadIdx.x;
    const int lane = tid & 63;
    const int l    = lane & 15;
    const int q    = lane >> 4;
    const int wu   = __builtin_amdgcn_readfirstlane(tid >> 6);
    const int r0   = blockIdx.x * ROWS;
    float* pw = (float*)(smem + 17408) + wu * (64 * 20);   // per-wave staging, stride 20

    // ---- phase 1: raw inputs -> h0 bf16 (BN folded into W0); xc passthrough ----
    for (int idx = tid; idx < 64 * 64; idx += 256) {
        int r = idx >> 6, j = idx & 63;
        float h = 0.f;
        if (j < 48) {
            int row = r0 + r;
            h = (j < 32) ? x[(size_t)row * 64 + 32 + j] : c[(size_t)row * 16 + (j - 32)];
        }
        h0[r * 72 + j] = f2bf(h);
    }
    for (int idx = tid; idx < 64 * 8; idx += 256) {
        int r = idx >> 3, ch = idx & 7;
        float4v v = *(const float4v*)(x + (size_t)(r0 + r) * 64 + 32 + ch * 4);
        *(float4v*)(out + (size_t)(r0 + r) * 64 + 32 + ch * 4) = v;
    }
    __syncthreads();

    // ---- phase 2: GEMM0  h1 = swish(h0 @ W0' + b0'), M=64 N=128 K=64(padded) ----
    {
        float4v acc[2][4];
        float4v z = {0.f, 0.f, 0.f, 0.f};
        #pragma unroll
        for (int nt = 0; nt < 2; ++nt)
            #pragma unroll
            for (int mt = 0; mt < 4; ++mt) acc[nt][mt] = z;
        #pragma unroll
        for (int ks = 0; ks < 2; ++ks) {
            short8 a[4];
            #pragma unroll
            for (int mt = 0; mt < 4; ++mt)
                a[mt] = *(const short8*)(h0 + (mt * 16 + l) * 72 + ks * 32 + (q << 3));
            #pragma unroll
            for (int nt = 0; nt < 2; ++nt) {
                int n0 = (wu * 2 + nt) * 16;
                short8 b = *(const short8*)(Wt0 + (n0 + l) * 64 + ks * 32 + (q << 3));
                #pragma unroll
                for (int mt = 0; mt < 4; ++mt)
                    acc[nt][mt] = __builtin_amdgcn_mfma_f32_16x16x32_bf16(a[mt], b, acc[nt][mt], 0, 0, 0);
            }
        }
        #pragma unroll
        for (int nt = 0; nt < 2; ++nt) {
            int n0 = (wu * 2 + nt) * 16;
            float bb = b0p[n0 + l];
            #pragma unroll
            for (int mt = 0; mt < 4; ++mt)
                #pragma unroll
                for (int r = 0; r < 4; ++r)
                    h1[(mt * 16 + q * 4 + r) * 136 + n0 + l] = f2bf(swish_f(acc[nt][mt][r] + bb));
        }
    }
    __syncthreads();

    // ---- phase 3: GEMM1  h2 = swish(h1 @ W1 + b1), M=64 N=128 K=128 ----
    {
        float4v acc[2][4];
        float4v z = {0.f, 0.f, 0.f, 0.f};
        #pragma unroll
        for (int nt = 0; nt < 2; ++nt)
            #pragma unroll
            for (int mt = 0; mt < 4; ++mt) acc[nt][mt] = z;
        #pragma unroll
        for (int ks = 0; ks < 4; ++ks) {
            short8 a[4];
            #pragma unroll
            for (int mt = 0; mt < 4; ++mt)
                a[mt] = *(const short8*)(h1 + (mt * 16 + l) * 136 + ks * 32 + (q << 3));
            #pragma unroll
            for (int nt = 0; nt < 2; ++nt) {
                int n0 = (wu * 2 + nt) * 16;
                short8 b = *(const short8*)(Wt1 + (n0 + l) * 128 + ks * 32 + (q << 3));
                #pragma unroll
                for (int mt = 0; mt < 4; ++mt)
                    acc[nt][mt] = __builtin_amdgcn_mfma_f32_16x16x32_bf16(a[mt], b, acc[nt][mt], 0, 0, 0);
            }
        }
        #pragma unroll
        for (int nt = 0; nt < 2; ++nt) {
            int n0 = (wu * 2 + nt) * 16;
            float bb = b1[n0 + l];
            #pragma unroll
            for (int mt = 0; mt < 4; ++mt)
                #pragma unroll
                for (int r = 0; r < 4; ++r)
                    h2[(mt * 16 + q * 4 + r) * 136 + n0 + l] = f2bf(swish_f(acc[nt][mt][r] + bb));
        }
    }
    __syncthreads();   // h1 dead -> pw reuses region B; h2 live in region A

    // ---- phase 4: h2 B-fragments resident in registers (pass-invariant) ----
    short8 bf[4][4];   // [ks][smt]
    #pragma unroll
    for (int ks = 0; ks < 4; ++ks)
        #pragma unroll
        for (int smt = 0; smt < 4; ++smt)
            bf[ks][smt] = *(const short8*)(h2 + (smt * 16 + l) * 136 + ks * 32 + (q << 3));

    float ld_local = 0.f;
    float yreg[8];
    for (int pass = 0; pass < 8; ++pass) {
        const int d = wu * 8 + pass;
        float t = x[(size_t)(r0 + lane) * 64 + d];   // issued early, consumed after stage W
        bool inb = (t >= 0.f) && (t <= 1.f);
        float tc = fminf(fmaxf(t, 0.f), 1.f);
        float pr[16];
        float4v z = {0.f, 0.f, 0.f, 0.f};

        // ======== jt=0 : knot widths ========
        {
            float4v acc[4] = {z, z, z, z};
            #pragma unroll
            for (int ks = 0; ks < 4; ++ks) {
                short8 a = *(const short8*)(Wt2 + (size_t)(d * 48 + l) * 128 + ks * 32 + (q << 3));
                #pragma unroll
                for (int smt = 0; smt < 4; ++smt)
                    acc[smt] = __builtin_amdgcn_mfma_f32_16x16x32_bf16(a, bf[ks][smt], acc[smt], 0, 0, 0);
            }
            float4v bj = *(const float4v*)(b2p + d * 48 + (q << 2));
            #pragma unroll
            for (int smt = 0; smt < 4; ++smt)
                *(float4v*)(pw + (smt * 16 + l) * 20 + (q << 2)) = acc[smt] + bj;
            asm volatile("s_waitcnt lgkmcnt(0)" ::: "memory");
            #pragma unroll
            for (int c2 = 0; c2 < 4; ++c2)
                *(float4v*)(pr + c2 * 4) = *(const float4v*)(pw + lane * 20 + c2 * 4);
        }
        float mW = pr[0];
        #pragma unroll
        for (int i = 1; i < 16; ++i) mW = fmaxf(mW, pr[i]);
        float sW = 0.f;
        #pragma unroll
        for (int i = 0; i < 16; ++i) { pr[i] = __expf(pr[i] - mW); sW += pr[i]; }
        float invW = 1.f / sW;
        float cum = 0.f, xkb = 0.f, dxb = pr[0] * invW;
        int idx = 0;
        #pragma unroll
        for (int i = 0; i < 16; ++i) {
            float dxi = pr[i] * invW;
            bool cnd = (tc >= cum);
            idx = cnd ? i   : idx;
            xkb = cnd ? cum : xkb;
            dxb = cnd ? dxi : dxb;
            cum += dxi;
        }

        // ======== jt=1 : knot heights ========
        {
            float4v acc[4] = {z, z, z, z};
            #pragma unroll
            for (int ks = 0; ks < 4; ++ks) {
                short8 a = *(const short8*)(Wt2 + (size_t)(d * 48 + 16 + l) * 128 + ks * 32 + (q << 3));
                #pragma unroll
                for (int smt = 0; smt < 4; ++smt)
                    acc[smt] = __builtin_amdgcn_mfma_f32_16x16x32_bf16(a, bf[ks][smt], acc[smt], 0, 0, 0);
            }
            float4v bj = *(const float4v*)(b2p + d * 48 + 16 + (q << 2));
            #pragma unroll
            for (int smt = 0; smt < 4; ++smt)
                *(float4v*)(pw + (smt * 16 + l) * 20 + (q << 2)) = acc[smt] + bj;
            asm volatile("s_waitcnt lgkmcnt(0)" ::: "memory");
            #pragma unroll
            for (int c2 = 0; c2 < 4; ++c2)
                *(float4v*)(pr + c2 * 4) = *(const float4v*)(pw + lane * 20 + c2 * 4);
        }
        float mH = pr[0];
        #pragma unroll
        for (int i = 1; i < 16; ++i) mH = fmaxf(mH, pr[i]);
        float sH = 0.f;
        #pragma unroll
        for (int i = 0; i < 16; ++i) { pr[i] = __expf(pr[i] - mH); sH += pr[i]; }
        float invH = 1.f / sH;
        float ykb = 0.f, dyb = pr[0] * invH;
        #pragma unroll
        for (int i = 0; i < 16; ++i) {
            float dyi = pr[i] * invH;
            ykb += (i < idx) ? dyi : 0.f;
            dyb  = (i == idx) ? dyi : dyb;
        }

        // ======== jt=2 : slopes (only 2 values needed per lane) ========
        {
            float4v acc[4] = {z, z, z, z};
            #pragma unroll
            for (int ks = 0; ks < 4; ++ks) {
                short8 a = *(const short8*)(Wt2 + (size_t)(d * 48 + 32 + l) * 128 + ks * 32 + (q << 3));
                #pragma unroll
                for (int smt = 0; smt < 4; ++smt)
                    acc[smt] = __builtin_amdgcn_mfma_f32_16x16x32_bf16(a, bf[ks][smt], acc[smt], 0, 0, 0);
            }
            float4v bj = *(const float4v*)(b2p + d * 48 + 32 + (q << 2));
            #pragma unroll
            for (int smt = 0; smt < 4; ++smt)
                *(float4v*)(pw + (smt * 16 + l) * 20 + (q << 2)) = acc[smt] + bj;
            asm volatile("s_waitcnt lgkmcnt(0)" ::: "memory");
        }
        int i0 = (idx > 0)  ? idx - 1 : 0;
        int i1 = (idx < 15) ? idx     : 14;
        float pa0 = pw[lane * 20 + i0];
        float pa1 = pw[lane * 20 + i1];
        float d0 = (idx == 0)  ? 1.f : softplus_f(pa0);
        float d1 = (idx == 15) ? 1.f : softplus_f(pa1);

        float xi  = (tc - xkb) / dxb;
        float s   = dyb / dxb;
        float xim = 1.f - xi;
        float x1m = xi * xim;
        float den = s + (d0 + d1 - 2.f * s) * x1m;
        float y_in = ykb + dyb * (s * xi * xi + d0 * x1m) / den;
        float dydx = s * s * (d1 * xi * xi + 2.f * s * x1m + d0 * xim * xim) / (den * den);

        yreg[pass] = inb ? y_in : t;
        ld_local += inb ? __logf(dydx) : 0.f;
    }

    // ---- epilogue: y from registers; log_det reduction ----
    {
        float4v* o = (float4v*)(out + (size_t)(r0 + lane) * 64 + wu * 8);
        o[0] = *(const float4v*)(yreg);
        o[1] = *(const float4v*)(yreg + 4);
    }
    ldp[wu * 64 + lane] = ld_local;
    __syncthreads();
    if (tid < 64) {
        out[(size_t)N * 64 + r0 + tid] =
            ldp[tid] + ldp[64 + tid] + ldp[128 + tid] + ldp[192 + tid];
    }
}

extern "C" void kernel_launch(void* const* d_in, const int* in_sizes, int n_in,
                              void* d_out, int out_size, void* d_ws, size_t ws_size,
                              hipStream_t stream) {
    const float* x        = (const float*)d_in[0];
    const float* c        = (const float*)d_in[1];
    const float* bn_scale = (const float*)d_in[2];
    const float* bn_bias  = (const float*)d_in[3];
    const float* bn_mean  = (const float*)d_in[4];
    const float* bn_var   = (const float*)d_in[5];
    const float* W0       = (const float*)d_in[6];
    const float* b0       = (const float*)d_in[7];
    const float* W1       = (const float*)d_in[8];
    const float* b1       = (const float*)d_in[9];
    const float* W2       = (const float*)d_in[10];
    const float* b2       = (const float*)d_in[11];
    float* out = (float*)d_out;

    unsigned short* Wt0 = (unsigned short*)d_ws;           // 128*64
    unsigned short* Wt1 = Wt0 + 128 * 64;                  // 128*128
    unsigned short* Wt2 = Wt1 + 128 * 128;                 // 1536*128
    float*          b2p = (float*)(Wt2 + 1536 * 128);      // 32*48
    float*          b0p = b2p + 32 * 48;                   // 128

    const int N = in_sizes[0] / 64;
    prep_weights<<<28, 256, 0, stream>>>(W0, W1, W2, b0, b2,
                                         bn_scale, bn_bias, bn_mean, bn_var,
                                         Wt0, Wt1, Wt2, b0p, b2p);
    nsc_mfma<<<N / ROWS, 256, 0, stream>>>(x, c, Wt0, b0p, Wt1, b1, Wt2, b2p, out, N);
}

// Round 5
// 174.337 us; speedup vs baseline: 1.4275x; 1.4275x over previous
//
#include <hip/hip_runtime.h>
#include <math.h>

#define BN_EPS 1e-5f
#define ROWS 64

typedef __attribute__((ext_vector_type(8))) short short8;
typedef __attribute__((ext_vector_type(4))) float float4v;

__device__ __forceinline__ unsigned short f2bf(float f) {
    union { float f; unsigned int u; } v; v.f = f;
    unsigned int r = v.u + 0x7FFF + ((v.u >> 16) & 1);   // RNE
    return (unsigned short)(r >> 16);
}
__device__ __forceinline__ float softplus_f(float v) {
    float r = log1pf(__expf(-fabsf(v)));
    return v > 0.f ? v + r : r;
}
__device__ __forceinline__ float swish_f(float a) {
    return a / (1.f + __expf(-a));
}

// ---- prep: coalesced LDS-tiled transposes + BN fold into W0/b0 ----
// grid = 28 blocks x 256:
//   0..23  : W2 [128][1504] -> Wt2 [1536][128] bf16 (col remap d*47+j -> d*48+j, j=47 pad)
//   24..25 : W1 [128][128]  -> Wt1 [128][128] bf16
//   26     : W0 fold: Wt0[n][k] = bf16(W0[k][n]*a[k]) (k<48, pad to 64); b0p = b0 + bsh @ W0
//   27     : b2 pad -> b2p [32][48]
__global__ void prep_weights(const float* __restrict__ W0, const float* __restrict__ W1,
                             const float* __restrict__ W2, const float* __restrict__ b0,
                             const float* __restrict__ b2,
                             const float* __restrict__ bn_scale, const float* __restrict__ bn_bias,
                             const float* __restrict__ bn_mean, const float* __restrict__ bn_var,
                             unsigned short* __restrict__ Wt0, unsigned short* __restrict__ Wt1,
                             unsigned short* __restrict__ Wt2, float* __restrict__ b0p,
                             float* __restrict__ b2p) {
    __shared__ float lds[64 * 129 + 128];
    const int bid = blockIdx.x, tid = threadIdx.x;
    if (bid < 26) {
        const float* src;
        int rstride, c0;
        bool remap;
        if (bid < 24) { src = W2; rstride = 1504; c0 = bid * 64; remap = true; }
        else          { src = W1; rstride = 128;  c0 = (bid - 24) * 64; remap = false; }
        const int cl = tid & 63;
        const int cd = c0 + cl;
        int scol = cd;
        bool valid = true;
        if (remap) {
            int dd = cd / 48, j = cd - dd * 48;
            valid = (j < 47);
            scol = dd * 47 + j;
        }
        #pragma unroll 4
        for (int it = 0; it < 32; ++it) {
            int k = (tid >> 6) + it * 4;
            lds[cl * 129 + k] = valid ? src[k * rstride + scol] : 0.f;   // coalesced read
        }
        __syncthreads();
        unsigned short* dst = (bid < 24) ? Wt2 : Wt1;
        #pragma unroll 4
        for (int it = 0; it < 32; ++it) {
            int cl2 = (tid >> 7) + it * 2;
            int k = tid & 127;
            dst[(size_t)(c0 + cl2) * 128 + k] = f2bf(lds[cl2 * 129 + k]);  // coalesced write
        }
        return;
    }
    if (bid == 26) {
        float* a   = lds + 48 * 129;
        float* bsh = a + 48;
        if (tid < 48) {
            float av = bn_scale[tid] * rsqrtf(bn_var[tid] + BN_EPS);
            a[tid] = av;
            bsh[tid] = bn_bias[tid] - bn_mean[tid] * av;
        }
        for (int idx = tid; idx < 48 * 128; idx += 256) {
            int k = idx >> 7, n = idx & 127;
            lds[k * 129 + n] = W0[k * 128 + n];
        }
        __syncthreads();
        #pragma unroll 4
        for (int it = 0; it < 32; ++it) {
            int n = (tid >> 6) + it * 4;
            int k = tid & 63;
            float v = (k < 48) ? lds[k * 129 + n] * a[k] : 0.f;
            Wt0[n * 64 + k] = f2bf(v);
        }
        if (tid < 128) {
            float s = b0[tid];
            #pragma unroll
            for (int k = 0; k < 48; ++k) s += bsh[k] * lds[k * 129 + tid];
            b0p[tid] = s;
        }
        return;
    }
    for (int e = tid; e < 32 * 48; e += 256) {
        int dd = e / 48, j = e - dd * 48;
        b2p[e] = (j < 47) ? b2[dd * 47 + j] : 0.f;
    }
}

__launch_bounds__(256, 4)
__global__ void nsc_mfma(const float* __restrict__ x, const float* __restrict__ c,
                         const unsigned short* __restrict__ Wt0, const float* __restrict__ b0p,
                         const unsigned short* __restrict__ Wt1, const float* __restrict__ b1,
                         const unsigned short* __restrict__ Wt2, const float* __restrict__ b2p,
                         float* __restrict__ out, int N) {
    // region A [0,17408):       h0 [64][72] bf16  ->  h2 [64][136] bf16 (live through GEMM2)
    // region B [17408,38912):   h1 [64][136] bf16 ->  pw 4x[64][20] f32 (20480) + ldp [4][64] f32
    __shared__ __align__(16) char smem[38912];
    unsigned short* h0 = (unsigned short*)smem;            // stride 72
    unsigned short* h2 = (unsigned short*)smem;            // stride 136
    unsigned short* h1 = (unsigned short*)(smem + 17408);  // stride 136
    float*          ldp = (float*)(smem + 17408 + 20480);  // [4][64]

    const int tid  = threadIdx.x;
    const int lane = tid & 63;
    const int l    = lane & 15;
    const int q    = lane >> 4;
    const int wu   = __builtin_amdgcn_readfirstlane(tid >> 6);
    const int r0   = blockIdx.x * ROWS;
    float* pw = (float*)(smem + 17408) + wu * (64 * 20);   // per-wave staging, stride 20

    // ---- phase 1: raw inputs -> h0 bf16 (BN folded into W0); xc passthrough ----
    for (int idx = tid; idx < 64 * 64; idx += 256) {
        int r = idx >> 6, j = idx & 63;
        float h = 0.f;
        if (j < 48) {
            int row = r0 + r;
            h = (j < 32) ? x[(size_t)row * 64 + 32 + j] : c[(size_t)row * 16 + (j - 32)];
        }
        h0[r * 72 + j] = f2bf(h);
    }
    for (int idx = tid; idx < 64 * 8; idx += 256) {
        int r = idx >> 3, ch = idx & 7;
        float4v v = *(const float4v*)(x + (size_t)(r0 + r) * 64 + 32 + ch * 4);
        *(float4v*)(out + (size_t)(r0 + r) * 64 + 32 + ch * 4) = v;
    }
    __syncthreads();

    // ---- phase 2: GEMM0  h1 = swish(h0 @ W0' + b0'), M=64 N=128 K=64(padded) ----
    {
        float4v acc[2][4];
        float4v z = {0.f, 0.f, 0.f, 0.f};
        #pragma unroll
        for (int nt = 0; nt < 2; ++nt)
            #pragma unroll
            for (int mt = 0; mt < 4; ++mt) acc[nt][mt] = z;
        #pragma unroll
        for (int ks = 0; ks < 2; ++ks) {
            short8 a[4];
            #pragma unroll
            for (int mt = 0; mt < 4; ++mt)
                a[mt] = *(const short8*)(h0 + (mt * 16 + l) * 72 + ks * 32 + (q << 3));
            #pragma unroll
            for (int nt = 0; nt < 2; ++nt) {
                int n0 = (wu * 2 + nt) * 16;
                short8 b = *(const short8*)(Wt0 + (n0 + l) * 64 + ks * 32 + (q << 3));
                #pragma unroll
                for (int mt = 0; mt < 4; ++mt)
                    acc[nt][mt] = __builtin_amdgcn_mfma_f32_16x16x32_bf16(a[mt], b, acc[nt][mt], 0, 0, 0);
            }
        }
        #pragma unroll
        for (int nt = 0; nt < 2; ++nt) {
            int n0 = (wu * 2 + nt) * 16;
            float bb = b0p[n0 + l];
            #pragma unroll
            for (int mt = 0; mt < 4; ++mt)
                #pragma unroll
                for (int r = 0; r < 4; ++r)
                    h1[(mt * 16 + q * 4 + r) * 136 + n0 + l] = f2bf(swish_f(acc[nt][mt][r] + bb));
        }
    }
    __syncthreads();

    // ---- phase 3: GEMM1  h2 = swish(h1 @ W1 + b1), M=64 N=128 K=128 ----
    {
        float4v acc[2][4];
        float4v z = {0.f, 0.f, 0.f, 0.f};
        #pragma unroll
        for (int nt = 0; nt < 2; ++nt)
            #pragma unroll
            for (int mt = 0; mt < 4; ++mt) acc[nt][mt] = z;
        #pragma unroll
        for (int ks = 0; ks < 4; ++ks) {
            short8 a[4];
            #pragma unroll
            for (int mt = 0; mt < 4; ++mt)
                a[mt] = *(const short8*)(h1 + (mt * 16 + l) * 136 + ks * 32 + (q << 3));
            #pragma unroll
            for (int nt = 0; nt < 2; ++nt) {
                int n0 = (wu * 2 + nt) * 16;
                short8 b = *(const short8*)(Wt1 + (n0 + l) * 128 + ks * 32 + (q << 3));
                #pragma unroll
                for (int mt = 0; mt < 4; ++mt)
                    acc[nt][mt] = __builtin_amdgcn_mfma_f32_16x16x32_bf16(a[mt], b, acc[nt][mt], 0, 0, 0);
            }
        }
        #pragma unroll
        for (int nt = 0; nt < 2; ++nt) {
            int n0 = (wu * 2 + nt) * 16;
            float bb = b1[n0 + l];
            #pragma unroll
            for (int mt = 0; mt < 4; ++mt)
                #pragma unroll
                for (int r = 0; r < 4; ++r)
                    h2[(mt * 16 + q * 4 + r) * 136 + n0 + l] = f2bf(swish_f(acc[nt][mt][r] + bb));
        }
    }
    __syncthreads();   // h1 dead -> pw reuses region B; h2 live in region A

    // ---- phase 4: GEMM2 (swapped: p^T tiles) + 3-stage spline ----
    // Round-3 register structure (no-spill proven): B-fragments transient in ks loop,
    // acc[3][4] live. Do NOT make bf pass-resident — round 4 showed it spills (FETCH 304MB).
    float ld_local = 0.f;
    float yreg[8];
    for (int pass = 0; pass < 8; ++pass) {
        const int d = wu * 8 + pass;
        float t = x[(size_t)(r0 + lane) * 64 + d];   // issued early, consumed after stage W
        bool inb = (t >= 0.f) && (t <= 1.f);
        float tc = fminf(fmaxf(t, 0.f), 1.f);

        float4v acc[3][4];
        float4v z = {0.f, 0.f, 0.f, 0.f};
        #pragma unroll
        for (int jt = 0; jt < 3; ++jt)
            #pragma unroll
            for (int smt = 0; smt < 4; ++smt) acc[jt][smt] = z;
        #pragma unroll
        for (int ks = 0; ks < 4; ++ks) {
            short8 bf[4];
            #pragma unroll
            for (int smt = 0; smt < 4; ++smt)
                bf[smt] = *(const short8*)(h2 + (smt * 16 + l) * 136 + ks * 32 + (q << 3));
            #pragma unroll
            for (int jt = 0; jt < 3; ++jt) {
                short8 a = *(const short8*)(Wt2 + (size_t)(d * 48 + jt * 16 + l) * 128 + ks * 32 + (q << 3));
                #pragma unroll
                for (int smt = 0; smt < 4; ++smt)
                    acc[jt][smt] = __builtin_amdgcn_mfma_f32_16x16x32_bf16(a, bf[smt], acc[jt][smt], 0, 0, 0);
            }
        }

        float pr[16];
        // ---- stage W (jt=0): softmax + bin search ----
        {
            float4v bj = *(const float4v*)(b2p + d * 48 + (q << 2));
            #pragma unroll
            for (int smt = 0; smt < 4; ++smt)
                *(float4v*)(pw + (smt * 16 + l) * 20 + (q << 2)) = acc[0][smt] + bj;
            asm volatile("s_waitcnt lgkmcnt(0)" ::: "memory");
            #pragma unroll
            for (int c2 = 0; c2 < 4; ++c2)
                *(float4v*)(pr + c2 * 4) = *(const float4v*)(pw + lane * 20 + c2 * 4);
        }
        float mW = pr[0];
        #pragma unroll
        for (int i = 1; i < 16; ++i) mW = fmaxf(mW, pr[i]);
        float sW = 0.f;
        #pragma unroll
        for (int i = 0; i < 16; ++i) { pr[i] = __expf(pr[i] - mW); sW += pr[i]; }
        float invW = 1.f / sW;
        float cum = 0.f, xkb = 0.f, dxb = pr[0] * invW;
        int idx = 0;
        #pragma unroll
        for (int i = 0; i < 16; ++i) {
            float dxi = pr[i] * invW;
            bool cnd = (tc >= cum);
            idx = cnd ? i   : idx;
            xkb = cnd ? cum : xkb;
            dxb = cnd ? dxi : dxb;
            cum += dxi;
        }

        // ---- stage H (jt=1): softmax + ykb/dyb ----
        {
            float4v bj = *(const float4v*)(b2p + d * 48 + 16 + (q << 2));
            #pragma unroll
            for (int smt = 0; smt < 4; ++smt)
                *(float4v*)(pw + (smt * 16 + l) * 20 + (q << 2)) = acc[1][smt] + bj;
            asm volatile("s_waitcnt lgkmcnt(0)" ::: "memory");
            #pragma unroll
            for (int c2 = 0; c2 < 4; ++c2)
                *(float4v*)(pr + c2 * 4) = *(const float4v*)(pw + lane * 20 + c2 * 4);
        }
        float mH = pr[0];
        #pragma unroll
        for (int i = 1; i < 16; ++i) mH = fmaxf(mH, pr[i]);
        float sH = 0.f;
        #pragma unroll
        for (int i = 0; i < 16; ++i) { pr[i] = __expf(pr[i] - mH); sH += pr[i]; }
        float invH = 1.f / sH;
        float ykb = 0.f, dyb = pr[0] * invH;
        #pragma unroll
        for (int i = 0; i < 16; ++i) {
            float dyi = pr[i] * invH;
            ykb += (i < idx) ? dyi : 0.f;
            dyb  = (i == idx) ? dyi : dyb;
        }

        // ---- stage D (jt=2): only 2 slope values needed per lane ----
        {
            float4v bj = *(const float4v*)(b2p + d * 48 + 32 + (q << 2));
            #pragma unroll
            for (int smt = 0; smt < 4; ++smt)
                *(float4v*)(pw + (smt * 16 + l) * 20 + (q << 2)) = acc[2][smt] + bj;
            asm volatile("s_waitcnt lgkmcnt(0)" ::: "memory");
        }
        int i0 = (idx > 0)  ? idx - 1 : 0;
        int i1 = (idx < 15) ? idx     : 14;
        float pa0 = pw[lane * 20 + i0];
        float pa1 = pw[lane * 20 + i1];
        float d0 = (idx == 0)  ? 1.f : softplus_f(pa0);
        float d1 = (idx == 15) ? 1.f : softplus_f(pa1);

        float xi  = (tc - xkb) / dxb;
        float s   = dyb / dxb;
        float xim = 1.f - xi;
        float x1m = xi * xim;
        float den = s + (d0 + d1 - 2.f * s) * x1m;
        float y_in = ykb + dyb * (s * xi * xi + d0 * x1m) / den;
        float dydx = s * s * (d1 * xi * xi + 2.f * s * x1m + d0 * xim * xim) / (den * den);

        yreg[pass] = inb ? y_in : t;
        ld_local += inb ? __logf(dydx) : 0.f;
    }

    // ---- epilogue: y from registers; log_det reduction ----
    {
        float4v* o = (float4v*)(out + (size_t)(r0 + lane) * 64 + wu * 8);
        o[0] = *(const float4v*)(yreg);
        o[1] = *(const float4v*)(yreg + 4);
    }
    ldp[wu * 64 + lane] = ld_local;
    __syncthreads();
    if (tid < 64) {
        out[(size_t)N * 64 + r0 + tid] =
            ldp[tid] + ldp[64 + tid] + ldp[128 + tid] + ldp[192 + tid];
    }
}

extern "C" void kernel_launch(void* const* d_in, const int* in_sizes, int n_in,
                              void* d_out, int out_size, void* d_ws, size_t ws_size,
                              hipStream_t stream) {
    const float* x        = (const float*)d_in[0];
    const float* c        = (const float*)d_in[1];
    const float* bn_scale = (const float*)d_in[2];
    const float* bn_bias  = (const float*)d_in[3];
    const float* bn_mean  = (const float*)d_in[4];
    const float* bn_var   = (const float*)d_in[5];
    const float* W0       = (const float*)d_in[6];
    const float* b0       = (const float*)d_in[7];
    const float* W1       = (const float*)d_in[8];
    const float* b1       = (const float*)d_in[9];
    const float* W2       = (const float*)d_in[10];
    const float* b2       = (const float*)d_in[11];
    float* out = (float*)d_out;

    unsigned short* Wt0 = (unsigned short*)d_ws;           // 128*64
    unsigned short* Wt1 = Wt0 + 128 * 64;                  // 128*128
    unsigned short* Wt2 = Wt1 + 128 * 128;                 // 1536*128
    float*          b2p = (float*)(Wt2 + 1536 * 128);      // 32*48
    float*          b0p = b2p + 32 * 48;                   // 128

    const int N = in_sizes[0] / 64;
    prep_weights<<<28, 256, 0, stream>>>(W0, W1, W2, b0, b2,
                                         bn_scale, bn_bias, bn_mean, bn_var,
                                         Wt0, Wt1, Wt2, b0p, b2p);
    nsc_mfma<<<N / ROWS, 256, 0, stream>>>(x, c, Wt0, b0p, Wt1, b1, Wt2, b2p, out, N);
}

// Round 6
// 162.445 us; speedup vs baseline: 1.5320x; 1.0732x over previous
//
#include <hip/hip_runtime.h>
#include <math.h>

#define BN_EPS 1e-5f
#define ROWS 64

typedef __attribute__((ext_vector_type(8))) short short8;
typedef __attribute__((ext_vector_type(4))) float float4v;

__device__ __forceinline__ unsigned short f2bf(float f) {
    union { float f; unsigned int u; } v; v.f = f;
    unsigned int r = v.u + 0x7FFF + ((v.u >> 16) & 1);   // RNE
    return (unsigned short)(r >> 16);
}
__device__ __forceinline__ float softplus_f(float v) {
    float e = __expf(-fabsf(v));
    float r = __logf(1.f + e);
    return v > 0.f ? v + r : r;
}
__device__ __forceinline__ float swish_f(float a) {
    return a / (1.f + __expf(-a));
}

// ---- prep: WIDE elementwise (read-coalesced, write-scatter merged in L2) ----
// blocks 0..831 : Wt2 (1536x128) + Wt1 (128x128), 1 elem/thread, consecutive
//                 threads read consecutive source columns (coalesced loads).
// block  832    : W0 fold (BN absorbed) + b0p
// block  833    : b2 pad -> b2p [32][48]
#define PREP_WIDE_THREADS (1536 * 128 + 128 * 128)   // 212992 -> 832 blocks
__global__ void prep_weights(const float* __restrict__ W0, const float* __restrict__ W1,
                             const float* __restrict__ W2, const float* __restrict__ b0,
                             const float* __restrict__ b2,
                             const float* __restrict__ bn_scale, const float* __restrict__ bn_bias,
                             const float* __restrict__ bn_mean, const float* __restrict__ bn_var,
                             unsigned short* __restrict__ Wt0, unsigned short* __restrict__ Wt1,
                             unsigned short* __restrict__ Wt2, float* __restrict__ b0p,
                             float* __restrict__ b2p) {
    const int bid = blockIdx.x, tid = threadIdx.x;
    if (bid < 832) {
        int i = bid * 256 + tid;
        if (i < 1536 * 128) {
            // i = k*1536 + colp  (colp fastest -> coalesced read of W2 row k)
            int k = i / 1536, colp = i - k * 1536;
            int dd = colp / 48, j = colp - dd * 48;
            float v = (j < 47) ? W2[k * 1504 + dd * 47 + j] : 0.f;
            Wt2[(size_t)colp * 128 + k] = f2bf(v);
        } else {
            int i2 = i - 1536 * 128;     // i2 = k*128 + n
            int k = i2 >> 7, n = i2 & 127;
            Wt1[n * 128 + k] = f2bf(W1[k * 128 + n]);
        }
        return;
    }
    if (bid == 832) {
        __shared__ float lds[48 * 129 + 96];
        float* a   = lds + 48 * 129;
        float* bsh = a + 48;
        if (tid < 48) {
            float av = bn_scale[tid] * rsqrtf(bn_var[tid] + BN_EPS);
            a[tid] = av;
            bsh[tid] = bn_bias[tid] - bn_mean[tid] * av;
        }
        for (int idx = tid; idx < 48 * 128; idx += 256) {
            int k = idx >> 7, n = idx & 127;
            lds[k * 129 + n] = W0[k * 128 + n];
        }
        __syncthreads();
        #pragma unroll 4
        for (int it = 0; it < 32; ++it) {
            int n = (tid >> 6) + it * 4;
            int k = tid & 63;
            float v = (k < 48) ? lds[k * 129 + n] * a[k] : 0.f;
            Wt0[n * 64 + k] = f2bf(v);
        }
        if (tid < 128) {
            float s = b0[tid];
            #pragma unroll
            for (int k = 0; k < 48; ++k) s += bsh[k] * lds[k * 129 + tid];
            b0p[tid] = s;
        }
        return;
    }
    for (int e = tid; e < 32 * 48; e += 256) {
        int dd = e / 48, j = e - dd * 48;
        b2p[e] = (j < 47) ? b2[dd * 47 + j] : 0.f;
    }
}

__launch_bounds__(256, 4)
__global__ void nsc_mfma(const float* __restrict__ x, const float* __restrict__ c,
                         const unsigned short* __restrict__ Wt0, const float* __restrict__ b0p,
                         const unsigned short* __restrict__ Wt1, const float* __restrict__ b1,
                         const unsigned short* __restrict__ Wt2, const float* __restrict__ b2p,
                         float* __restrict__ out, int N) {
    // region A [0,17408):       h0 [64][72] bf16  ->  h2 [64][136] bf16 (live through GEMM2)
    // region B [17408,38912):   h1 [64][136] bf16 ->  pw 4x[64][20] f32 (20480) + ldp [4][64] f32
    __shared__ __align__(16) char smem[38912];
    unsigned short* h0 = (unsigned short*)smem;            // stride 72
    unsigned short* h2 = (unsigned short*)smem;            // stride 136
    unsigned short* h1 = (unsigned short*)(smem + 17408);  // stride 136
    float*          ldp = (float*)(smem + 17408 + 20480);  // [4][64]

    const int tid  = threadIdx.x;
    const int lane = tid & 63;
    const int l    = lane & 15;
    const int q    = lane >> 4;
    const int wu   = __builtin_amdgcn_readfirstlane(tid >> 6);
    const int r0   = blockIdx.x * ROWS;
    float* pw = (float*)(smem + 17408) + wu * (64 * 20);   // per-wave staging, stride 20

    // ---- phase 1: raw inputs -> h0 bf16 (BN folded into W0); xc passthrough ----
    for (int idx = tid; idx < 64 * 64; idx += 256) {
        int r = idx >> 6, j = idx & 63;
        float h = 0.f;
        if (j < 48) {
            int row = r0 + r;
            h = (j < 32) ? x[(size_t)row * 64 + 32 + j] : c[(size_t)row * 16 + (j - 32)];
        }
        h0[r * 72 + j] = f2bf(h);
    }
    for (int idx = tid; idx < 64 * 8; idx += 256) {
        int r = idx >> 3, ch = idx & 7;
        float4v v = *(const float4v*)(x + (size_t)(r0 + r) * 64 + 32 + ch * 4);
        *(float4v*)(out + (size_t)(r0 + r) * 64 + 32 + ch * 4) = v;
    }
    __syncthreads();

    // ---- phase 2: GEMM0  h1 = swish(h0 @ W0' + b0'), M=64 N=128 K=64(padded) ----
    {
        float4v acc[2][4];
        float4v z = {0.f, 0.f, 0.f, 0.f};
        #pragma unroll
        for (int nt = 0; nt < 2; ++nt)
            #pragma unroll
            for (int mt = 0; mt < 4; ++mt) acc[nt][mt] = z;
        #pragma unroll
        for (int ks = 0; ks < 2; ++ks) {
            short8 a[4];
            #pragma unroll
            for (int mt = 0; mt < 4; ++mt)
                a[mt] = *(const short8*)(h0 + (mt * 16 + l) * 72 + ks * 32 + (q << 3));
            #pragma unroll
            for (int nt = 0; nt < 2; ++nt) {
                int n0 = (wu * 2 + nt) * 16;
                short8 b = *(const short8*)(Wt0 + (n0 + l) * 64 + ks * 32 + (q << 3));
                #pragma unroll
                for (int mt = 0; mt < 4; ++mt)
                    acc[nt][mt] = __builtin_amdgcn_mfma_f32_16x16x32_bf16(a[mt], b, acc[nt][mt], 0, 0, 0);
            }
        }
        #pragma unroll
        for (int nt = 0; nt < 2; ++nt) {
            int n0 = (wu * 2 + nt) * 16;
            float bb = b0p[n0 + l];
            #pragma unroll
            for (int mt = 0; mt < 4; ++mt)
                #pragma unroll
                for (int r = 0; r < 4; ++r)
                    h1[(mt * 16 + q * 4 + r) * 136 + n0 + l] = f2bf(swish_f(acc[nt][mt][r] + bb));
        }
    }
    __syncthreads();

    // ---- phase 3: GEMM1  h2 = swish(h1 @ W1 + b1), M=64 N=128 K=128 ----
    {
        float4v acc[2][4];
        float4v z = {0.f, 0.f, 0.f, 0.f};
        #pragma unroll
        for (int nt = 0; nt < 2; ++nt)
            #pragma unroll
            for (int mt = 0; mt < 4; ++mt) acc[nt][mt] = z;
        #pragma unroll
        for (int ks = 0; ks < 4; ++ks) {
            short8 a[4];
            #pragma unroll
            for (int mt = 0; mt < 4; ++mt)
                a[mt] = *(const short8*)(h1 + (mt * 16 + l) * 136 + ks * 32 + (q << 3));
            #pragma unroll
            for (int nt = 0; nt < 2; ++nt) {
                int n0 = (wu * 2 + nt) * 16;
                short8 b = *(const short8*)(Wt1 + (n0 + l) * 128 + ks * 32 + (q << 3));
                #pragma unroll
                for (int mt = 0; mt < 4; ++mt)
                    acc[nt][mt] = __builtin_amdgcn_mfma_f32_16x16x32_bf16(a[mt], b, acc[nt][mt], 0, 0, 0);
            }
        }
        #pragma unroll
        for (int nt = 0; nt < 2; ++nt) {
            int n0 = (wu * 2 + nt) * 16;
            float bb = b1[n0 + l];
            #pragma unroll
            for (int mt = 0; mt < 4; ++mt)
                #pragma unroll
                for (int r = 0; r < 4; ++r)
                    h2[(mt * 16 + q * 4 + r) * 136 + n0 + l] = f2bf(swish_f(acc[nt][mt][r] + bb));
        }
    }
    __syncthreads();   // h1 dead -> pw reuses region B; h2 live in region A

    // ---- phase 4: GEMM2 (swapped: p^T tiles) + 3-stage spline ----
    // Round-3 register structure (no-spill proven). Do NOT make bf pass-resident —
    // round 4 showed it spills (FETCH 304MB). No asm fences: pw is per-wave private,
    // DS ops within a wave are in-order, compiler preserves may-alias write->read order.
    float ld_local = 0.f;
    float yreg[8];
    for (int pass = 0; pass < 8; ++pass) {
        const int d = wu * 8 + pass;
        float t = x[(size_t)(r0 + lane) * 64 + d];   // issued early, consumed after stage W
        bool inb = (t >= 0.f) && (t <= 1.f);
        float tc = fminf(fmaxf(t, 0.f), 1.f);

        float4v acc[3][4];
        float4v z = {0.f, 0.f, 0.f, 0.f};
        #pragma unroll
        for (int jt = 0; jt < 3; ++jt)
            #pragma unroll
            for (int smt = 0; smt < 4; ++smt) acc[jt][smt] = z;
        #pragma unroll
        for (int ks = 0; ks < 4; ++ks) {
            short8 bf[4];
            #pragma unroll
            for (int smt = 0; smt < 4; ++smt)
                bf[smt] = *(const short8*)(h2 + (smt * 16 + l) * 136 + ks * 32 + (q << 3));
            #pragma unroll
            for (int jt = 0; jt < 3; ++jt) {
                short8 a = *(const short8*)(Wt2 + (size_t)(d * 48 + jt * 16 + l) * 128 + ks * 32 + (q << 3));
                #pragma unroll
                for (int smt = 0; smt < 4; ++smt)
                    acc[jt][smt] = __builtin_amdgcn_mfma_f32_16x16x32_bf16(a, bf[smt], acc[jt][smt], 0, 0, 0);
            }
        }

        float pr[16];
        // ---- stage W (jt=0): softmax + bin search ----
        {
            float4v bj = *(const float4v*)(b2p + d * 48 + (q << 2));
            #pragma unroll
            for (int smt = 0; smt < 4; ++smt)
                *(float4v*)(pw + (smt * 16 + l) * 20 + (q << 2)) = acc[0][smt] + bj;
            #pragma unroll
            for (int c2 = 0; c2 < 4; ++c2)
                *(float4v*)(pr + c2 * 4) = *(const float4v*)(pw + lane * 20 + c2 * 4);
        }
        float mW = pr[0];
        #pragma unroll
        for (int i = 1; i < 16; ++i) mW = fmaxf(mW, pr[i]);
        float sW = 0.f;
        #pragma unroll
        for (int i = 0; i < 16; ++i) { pr[i] = __expf(pr[i] - mW); sW += pr[i]; }
        float invW = 1.f / sW;
        float cum = 0.f, xkb = 0.f, dxb = pr[0] * invW;
        int idx = 0;
        #pragma unroll
        for (int i = 0; i < 16; ++i) {
            float dxi = pr[i] * invW;
            bool cnd = (tc >= cum);
            idx = cnd ? i   : idx;
            xkb = cnd ? cum : xkb;
            dxb = cnd ? dxi : dxb;
            cum += dxi;
        }

        // ---- stage H (jt=1): softmax + ykb/dyb ----
        {
            float4v bj = *(const float4v*)(b2p + d * 48 + 16 + (q << 2));
            #pragma unroll
            for (int smt = 0; smt < 4; ++smt)
                *(float4v*)(pw + (smt * 16 + l) * 20 + (q << 2)) = acc[1][smt] + bj;
            #pragma unroll
            for (int c2 = 0; c2 < 4; ++c2)
                *(float4v*)(pr + c2 * 4) = *(const float4v*)(pw + lane * 20 + c2 * 4);
        }
        float mH = pr[0];
        #pragma unroll
        for (int i = 1; i < 16; ++i) mH = fmaxf(mH, pr[i]);
        float sH = 0.f;
        #pragma unroll
        for (int i = 0; i < 16; ++i) { pr[i] = __expf(pr[i] - mH); sH += pr[i]; }
        float invH = 1.f / sH;
        float ykb = 0.f, dyb = pr[0] * invH;
        #pragma unroll
        for (int i = 0; i < 16; ++i) {
            float dyi = pr[i] * invH;
            ykb += (i < idx) ? dyi : 0.f;
            dyb  = (i == idx) ? dyi : dyb;
        }

        // ---- stage D (jt=2): only 2 slope values needed per lane ----
        {
            float4v bj = *(const float4v*)(b2p + d * 48 + 32 + (q << 2));
            #pragma unroll
            for (int smt = 0; smt < 4; ++smt)
                *(float4v*)(pw + (smt * 16 + l) * 20 + (q << 2)) = acc[2][smt] + bj;
        }
        int i0 = (idx > 0)  ? idx - 1 : 0;
        int i1 = (idx < 15) ? idx     : 14;
        float pa0 = pw[lane * 20 + i0];
        float pa1 = pw[lane * 20 + i1];
        float d0 = (idx == 0)  ? 1.f : softplus_f(pa0);
        float d1 = (idx == 15) ? 1.f : softplus_f(pa1);

        float xi  = (tc - xkb) / dxb;
        float s   = dyb / dxb;
        float xim = 1.f - xi;
        float x1m = xi * xim;
        float den = s + (d0 + d1 - 2.f * s) * x1m;
        float y_in = ykb + dyb * (s * xi * xi + d0 * x1m) / den;
        float dydx = s * s * (d1 * xi * xi + 2.f * s * x1m + d0 * xim * xim) / (den * den);

        yreg[pass] = inb ? y_in : t;
        ld_local += inb ? __logf(dydx) : 0.f;
    }

    // ---- epilogue: y from registers; log_det reduction ----
    {
        float4v* o = (float4v*)(out + (size_t)(r0 + lane) * 64 + wu * 8);
        o[0] = *(const float4v*)(yreg);
        o[1] = *(const float4v*)(yreg + 4);
    }
    ldp[wu * 64 + lane] = ld_local;
    __syncthreads();
    if (tid < 64) {
        out[(size_t)N * 64 + r0 + tid] =
            ldp[tid] + ldp[64 + tid] + ldp[128 + tid] + ldp[192 + tid];
    }
}

extern "C" void kernel_launch(void* const* d_in, const int* in_sizes, int n_in,
                              void* d_out, int out_size, void* d_ws, size_t ws_size,
                              hipStream_t stream) {
    const float* x        = (const float*)d_in[0];
    const float* c        = (const float*)d_in[1];
    const float* bn_scale = (const float*)d_in[2];
    const float* bn_bias  = (const float*)d_in[3];
    const float* bn_mean  = (const float*)d_in[4];
    const float* bn_var   = (const float*)d_in[5];
    const float* W0       = (const float*)d_in[6];
    const float* b0       = (const float*)d_in[7];
    const float* W1       = (const float*)d_in[8];
    const float* b1       = (const float*)d_in[9];
    const float* W2       = (const float*)d_in[10];
    const float* b2       = (const float*)d_in[11];
    float* out = (float*)d_out;

    unsigned short* Wt0 = (unsigned short*)d_ws;           // 128*64
    unsigned short* Wt1 = Wt0 + 128 * 64;                  // 128*128
    unsigned short* Wt2 = Wt1 + 128 * 128;                 // 1536*128
    float*          b2p = (float*)(Wt2 + 1536 * 128);      // 32*48
    float*          b0p = b2p + 32 * 48;                   // 128

    const int N = in_sizes[0] / 64;
    prep_weights<<<834, 256, 0, stream>>>(W0, W1, W2, b0, b2,
                                          bn_scale, bn_bias, bn_mean, bn_var,
                                          Wt0, Wt1, Wt2, b0p, b2p);
    nsc_mfma<<<N / ROWS, 256, 0, stream>>>(x, c, Wt0, b0p, Wt1, b1, Wt2, b2p, out, N);
}